// Round 22
// baseline (87.055 us; speedup 1.0000x reference)
//
#include <hip/hip_runtime.h>
#include <math.h>

#define NLAT 360
#define NLON 720
#define LMAX 360
#define MMAX 361
#define KPADC 384   // stage-1 C-col space per bc: 192 kf x 2 (s)
#define KFP  192    // folded-k padded length (180 data + 12 zero pad)
#define FT2C 192    // radix-4 folded DFT cols (181 data + 11 zero pad)
#define FT2R 368    // FT rows (361 data + 7 zero pad)
#define NJ   32
#define PS   200    // Xs col stride (shorts)
#define YST  72     // Ys row stride (shorts)
#define PER_M_SH 12288   // shorts per mode: 2*32*192
#define XR_OFF 141312    // bytes: FT2R*FT2C*2

typedef __attribute__((ext_vector_type(4))) float f32x4;
typedef __attribute__((ext_vector_type(8))) short bf16x8;

__device__ __forceinline__ short f2bf(float f) {
    union { float f; unsigned u; } v; v.f = f;
    unsigned r = (v.u + 0x7FFFu + ((v.u >> 16) & 1u)) >> 16;
    return (short)r;
}

// --- kernel 0: radix-4 folded bf16 cosine-DFT matrix FT[m][n3] (r21) -------
__global__ __launch_bounds__(256) void fill_ft_kernel(short* __restrict__ FT2) {
    int idx = blockIdx.x * 256 + threadIdx.x;
    const int total = FT2R * FT2C;
    if (idx >= total) return;
    int n = idx % FT2C;
    int m = idx / FT2C;
    short val = 0;
    if (m < MMAX && n <= 180) {
        int t = (m * n) % NLON;
        float s, c;
        sincospif((float)t / 360.0f, &s, &c);
        val = f2bf((6.283185307179586f / 720.0f) * c);
    }
    FT2[idx] = val;
}

// ---- stage-2 tile-unit macros (r21 body; LDS base = WlH, tid -> tidl) -----
#define S2_GW(P, T)                                                             \
  { P##wa = *(const f32x4*)(wsp0 + (T) * 32);                                   \
    P##wb = *(const f32x4*)(wsp0 + (T) * 32 + 4);                               \
    P##wc = *(const f32x4*)(wsp1 + (T) * 32);                                   \
    P##wd = *(const f32x4*)(wsp1 + (T) * 32 + 4); }

#define S2_GB(P, T)                                                             \
  { P##ba = *(const bf16x8*)(be0 + (T) * 32);                                   \
    P##bb = *(const bf16x8*)(be1 + (T) * 32);                                   \
    P##bc = *(const bf16x8*)(bo0 + (T) * 32);                                   \
    P##bd = *(const bf16x8*)(bo1 + (T) * 32); }

#define S2_WRT(P, BUF)                                                          \
  { bf16x8 h0, h1;                                                              \
    _Pragma("unroll")                                                           \
    for (int e = 0; e < 4; ++e) {                                               \
      h0[e] = f2bf(P##wa[e]); h0[e + 4] = f2bf(P##wb[e]);                       \
      h1[e] = f2bf(P##wc[e]); h1[e + 4] = f2bf(P##wd[e]);                       \
    }                                                                           \
    *(bf16x8*)&WlH[(BUF) * 5440 + ldso0] = h0;                                  \
    *(bf16x8*)&WlH[(BUF) * 5440 + ldso1] = h1; }

#define S2_SYNC                                                                 \
    asm volatile("s_waitcnt lgkmcnt(0)" ::: "memory");                          \
    __builtin_amdgcn_s_barrier();                                               \
    __builtin_amdgcn_sched_barrier(0);

#define S2_CMP(P, BUF)                                                          \
  { bf16x8 aEf = *(const bf16x8*)&WlH[(BUF) * 5440 + aEo];                      \
    bf16x8 aOf = *(const bf16x8*)&WlH[(BUF) * 5440 + aOo];                      \
    accE0 = __builtin_amdgcn_mfma_f32_16x16x32_bf16(aEf, P##ba, accE0, 0, 0, 0);\
    accE1 = __builtin_amdgcn_mfma_f32_16x16x32_bf16(aEf, P##bb, accE1, 0, 0, 0);\
    accO0 = __builtin_amdgcn_mfma_f32_16x16x32_bf16(aOf, P##bc, accO0, 0, 0, 0);\
    accO1 = __builtin_amdgcn_mfma_f32_16x16x32_bf16(aOf, P##bd, accO1, 0, 0, 0);}

// ---------------- fused kernel: s2(chunk i) blocks + s1(chunk i+1) blocks --
// blockIdx.x < nb2  -> stage-2 role: 2 independent 4-m tile-units per block
//                      (halves; own 21.76KB LDS slice; lockstep barriers).
// blockIdx.x >= nb2 -> stage-1 role (r21 body, Ys 128 rows; panel id offset).
// Roles touch DIFFERENT EO buffers (eoR read / eoW write) -> no interaction.
__global__ __launch_bounds__(512) void fused_kernel(
        const float* __restrict__ x, const short* __restrict__ FT2,
        const float* __restrict__ W, float* __restrict__ out,
        const short* eoR, short* eoW,
        int m0_2, int m_hi_2, int nb2, int ntiles2,
        int m0_1, int m_hi_1) {
    __shared__ __align__(16) short U[34816];   // 69,632 B union
    const int tid = threadIdx.x;

    if ((int)blockIdx.x < nb2) {
        // ======================= stage-2 role ===========================
        const int half = tid >> 8;
        const int tidl = tid & 255;
        short* WlH = &U[half * 10880];
        int tile = (int)blockIdx.x * 2 + half;
        const bool dead = (tile >= ntiles2);
        if (dead) tile = 0;
        int bid = tile, mt = 0;
        for (;;) {
            const int c = 12 - ((m0_2 + mt * 4) >> 5);
            if (bid < c) break;
            bid -= c; ++mt;
        }
        const int ltile = ((m0_2 + mt * 4) >> 5) + bid;
        const int l0 = ltile * 32;              // even
        const int mb = m0_2 + mt * 4;

        const int wav  = tidl >> 6;             // 0..3 = m offset
        const int lane = tidl & 63;
        const int r    = lane & 15;
        const int kg   = (lane >> 4) * 8;

        const int m    = mb + wav;
        const int mc   = (m < m_hi_2) ? m : (m_hi_2 - 1);
        const int par  = mc & 1;
        const int mloc = mc - m0_2;

        const int srr = tidl >> 2;
        const int sq  = (tidl & 3) * 8;
        const int moff0 = srr >> 5,        loff0 = srr & 31;
        const int moff1 = (64 + srr) >> 5, loff1 = (64 + srr) & 31;
        int mst0 = mb + moff0; if (mst0 > MMAX - 1) mst0 = MMAX - 1;
        int mst1 = mb + moff1; if (mst1 > MMAX - 1) mst1 = MMAX - 1;
        int lst0 = l0 + loff0; if (lst0 > LMAX - 1) lst0 = LMAX - 1;
        int lst1 = l0 + loff1; if (lst1 > LMAX - 1) lst1 = LMAX - 1;
        const float* wsp0 = W + ((size_t)mst0 * LMAX + lst0) * NLAT + sq;
        const float* wsp1 = W + ((size_t)mst1 * LMAX + lst1) * NLAT + sq;
        const int ldso0 = ((moff0 * 2 + (loff0 & 1)) * 17 + (loff0 >> 1)) * 40 + sq;
        const int ldso1 = ((moff1 * 2 + (loff1 & 1)) * 17 + (loff1 >> 1)) * 40 + sq;

        const short* be0 = eoR + (((size_t)mloc * 2 + 0) * NJ + r)      * KFP + kg;
        const short* be1 = eoR + (((size_t)mloc * 2 + 0) * NJ + 16 + r) * KFP + kg;
        const short* bo0 = eoR + (((size_t)mloc * 2 + 1) * NJ + r)      * KFP + kg;
        const short* bo1 = eoR + (((size_t)mloc * 2 + 1) * NJ + 16 + r) * KFP + kg;

        const int aEo = ((wav * 2 + par) * 17 + r) * 40 + kg;
        const int aOo = ((wav * 2 + (1 - par)) * 17 + r) * 40 + kg;

        f32x4 accE0 = {0,0,0,0}, accE1 = {0,0,0,0}, accO0 = {0,0,0,0}, accO1 = {0,0,0,0};

        f32x4 Awa, Awb, Awc, Awd, Bwa, Bwb, Bwc, Bwd, Cwa, Cwb, Cwc, Cwd;
        bf16x8 Aba, Abb, Abc, Abd, Bba, Bbb, Bbc, Bbd, Cba, Cbb, Cbc, Cbd;

        S2_GW(A, 0); S2_GB(A, 0);
        S2_GW(B, 1); S2_GB(B, 1);
        S2_GW(C, 2); S2_GB(C, 2);

        S2_WRT(A, 0); S2_SYNC; S2_CMP(A, 0); S2_GW(A, 3); S2_GB(A, 3);
        S2_WRT(B, 1); S2_SYNC; S2_CMP(B, 1); S2_GW(B, 4); S2_GB(B, 4);
        S2_WRT(C, 0); S2_SYNC; S2_CMP(C, 0); S2_GW(C, 5); S2_GB(C, 5);
        S2_WRT(A, 1); S2_SYNC; S2_CMP(A, 1);
        S2_WRT(B, 0); S2_SYNC; S2_CMP(B, 0);
        S2_WRT(C, 1); S2_SYNC; S2_CMP(C, 1);

        const int rowg = (lane >> 4) * 4;
        if (m < m_hi_2 && !dead) {
            #pragma unroll
            for (int i = 0; i < 4; ++i) {
                const int R  = rowg + i;
                const int le = l0 + par + 2 * R;
                const int lo = l0 + 1 - par + 2 * R;
                const size_t b0 = (size_t)r * LMAX;
                const size_t b1 = (size_t)(16 + r) * LMAX;
                if (le < LMAX) {
                    out[(b0 + le) * MMAX + m] = accE0[i];
                    out[(b1 + le) * MMAX + m] = accE1[i];
                }
                if (lo < LMAX) {
                    out[(b0 + lo) * MMAX + m] = accO0[i];
                    out[(b1 + lo) * MMAX + m] = accO1[i];
                }
            }
        }
    } else {
        // ======================= stage-1 role ===========================
        short (*Xs)[64][PS] = (short (*)[64][PS])&U[0];   // 2*64*200 = 25,600 sh
        short* Ys = &U[25600];                            // 128*72 = 9,216 sh
        const int wav  = tid >> 6;
        const int lane = tid & 63;
        const int col0 = ((int)blockIdx.x - nb2) * 64;

        const int bc_blk = col0 / KPADC;
        const int kf0    = (col0 - bc_blk * KPADC) >> 1;

        // staging: radix-4 n-fold (r21 verbatim)
        for (int p = tid; p < 64 * 24; p += 512) {
            const int row = p / 24;
            const int c   = p - row * 24;
            const int gb  = col0 + row;
            const int bc  = gb / KPADC;
            const int q   = gb - bc * KPADC;
            const int kf  = q >> 1;
            const int s   = q & 1;
            const int klat = s ? (NLAT - 1 - kf) : kf;
            bf16x8 sv = {0,0,0,0,0,0,0,0}, dv = {0,0,0,0,0,0,0,0};
            if (kf < 180) {
                const float* xp = x + ((size_t)bc * NLAT + klat) * NLON;
                const int n0 = c * 8;
                f32x4 f0 = *(const f32x4*)(xp + n0);
                f32x4 f1 = *(const f32x4*)(xp + n0 + 4);
                f32x4 g0 = *(const f32x4*)(xp + n0 + 360);
                f32x4 g1 = *(const f32x4*)(xp + n0 + 364);
                f32x4 v0 = *(const f32x4*)(xp + 352 - n0);
                f32x4 v1 = *(const f32x4*)(xp + 356 - n0);
                f32x4 w0 = *(const f32x4*)(xp + 712 - n0);
                f32x4 w1 = *(const f32x4*)(xp + 716 - n0);
                const float t360 = xp[360 - n0];
                const float t720 = (c > 0) ? xp[720 - n0] : 0.0f;
                #pragma unroll
                for (int e = 0; e < 8; ++e) {
                    const int n3 = n0 + e;
                    const float a = (e < 4) ? f0[e] : f1[e - 4];
                    const float b = (e < 4) ? g0[e] : g1[e - 4];
                    float r3 = (e == 0) ? t360 : ((8 - e < 4) ? v0[(8 - e) & 3] : v1[(8 - e) & 3]);
                    float r7 = (e == 0) ? t720 : ((8 - e < 4) ? w0[(8 - e) & 3] : w1[(8 - e) & 3]);
                    if (n3 == 0 || n3 == 180) { r3 = 0.0f; r7 = 0.0f; }
                    sv[e] = f2bf((a + b) + (r3 + r7));
                    dv[e] = f2bf((a - b) - (r3 - r7));
                }
            }
            *(bf16x8*)&(*Xs)[row][c * 8] = sv;               // plane 0
            *(bf16x8*)&Xs[1][row][c * 8] = dv;               // plane 1
        }
        __syncthreads();

        const int r    = lane & 15;
        const int kg   = (lane >> 4) * 8;
        const int rowg = (lane >> 4) * 4;

        for (int mb = m0_1; mb < m_hi_1; mb += 256) {
            const int mwb = mb + wav * 32;
            const bool active = (mwb < m_hi_1);

            if (active) {
                int mE = mwb + 2 * r;     if (mE > FT2R - 1) mE = FT2R - 1;
                int mO = mwb + 2 * r + 1; if (mO > FT2R - 1) mO = FT2R - 1;
                const short* ape = FT2 + (size_t)mE * FT2C + kg;
                const short* apo = FT2 + (size_t)mO * FT2C + kg;

                f32x4 accE[4] = {{0,0,0,0},{0,0,0,0},{0,0,0,0},{0,0,0,0}};
                f32x4 accO[4] = {{0,0,0,0},{0,0,0,0},{0,0,0,0},{0,0,0,0}};

                bf16x8 AEc = *(const bf16x8*)ape;
                bf16x8 AOc = *(const bf16x8*)apo;
                #pragma unroll
                for (int t = 0; t < 6; ++t) {
                    bf16x8 AEn, AOn;
                    if (t < 5) {
                        AEn = *(const bf16x8*)(ape + (t + 1) * 32);
                        AOn = *(const bf16x8*)(apo + (t + 1) * 32);
                    }
                    #pragma unroll
                    for (int f = 0; f < 4; ++f) {
                        bf16x8 bS = *(const bf16x8*)&Xs[0][f * 16 + r][t * 32 + kg];
                        bf16x8 bD = *(const bf16x8*)&Xs[1][f * 16 + r][t * 32 + kg];
                        accE[f] = __builtin_amdgcn_mfma_f32_16x16x32_bf16(AEc, bS, accE[f], 0, 0, 0);
                        accO[f] = __builtin_amdgcn_mfma_f32_16x16x32_bf16(AOc, bD, accO[f], 0, 0, 0);
                    }
                    AEc = AEn; AOc = AOn;
                }

                // k-fold + Ys transpose (m_loc < 128 since chunk <= 128)
                #pragma unroll
                for (int f = 0; f < 4; ++f) {
                    const int kfl = (f * 16 + r) >> 1;
                    const int e   = r & 1;
                    const int yo  = e * 32 + kfl;
                    #pragma unroll
                    for (int i = 0; i < 4; ++i) {
                        float vE = accE[f][i];
                        float pE = __shfl_xor(vE, 1);
                        float valE = e ? (pE - vE) : (vE + pE);
                        float vO = accO[f][i];
                        float pO = __shfl_xor(vO, 1);
                        float valO = e ? (pO - vO) : (vO + pO);
                        const int mlE = wav * 32 + 2 * (rowg + i);
                        Ys[(size_t)mlE * YST + yo]       = f2bf(valE);
                        Ys[(size_t)(mlE + 1) * YST + yo] = f2bf(valO);
                    }
                }
            }
            __syncthreads();

            // coalesced EO store: one full 64B line per (m_loc, e)
            {
                const int m_loc = tid >> 1;
                const int e     = tid & 1;
                const int mg    = mb + m_loc;
                if (mg < m_hi_1) {
                    const short* src = &Ys[m_loc * YST + e * 32];
                    short* dst = eoW + (((size_t)(mg - m0_1) * 2 + e) * NJ + bc_blk) * KFP + kf0;
                    #pragma unroll
                    for (int j = 0; j < 4; ++j)
                        *(bf16x8*)(dst + j * 8) = *(const bf16x8*)(src + j * 8);
                }
            }
            __syncthreads();
        }
    }
}

extern "C" void kernel_launch(void* const* d_in, const int* in_sizes, int n_in,
                              void* d_out, int out_size, void* d_ws, size_t ws_size,
                              hipStream_t stream) {
    const float* x = (const float*)d_in[0];
    const float* w = (const float*)d_in[1];
    float* out = (float*)d_out;

    const long PER_M = (long)PER_M_SH * 2;   // 24,576 B per mode
    if (d_ws == nullptr || (long)ws_size <= XR_OFF + PER_M) return;
    const long avail = (long)ws_size - XR_OFF;
    long cmd = avail / (2 * PER_M); if (cmd > 128) cmd = 128;
    const bool dbuf = (cmd >= 24);
    long cm = dbuf ? cmd : (avail / PER_M);
    if (cm > 128) cm = 128;
    if (cm < 1) return;

    short* FT2 = (short*)d_ws;
    short* b0  = (short*)((char*)d_ws + XR_OFF);
    short* b1  = dbuf ? (b0 + cm * PER_M_SH) : b0;
    const int nc = (MMAX + (int)cm - 1) / (int)cm;

    auto ntilesf = [](int m0, int mhi) {
        int gym = (mhi - m0 + 3) / 4, n = 0;
        for (int t = 0; t < gym; ++t) n += 12 - ((m0 + t * 4) >> 5);
        return n;
    };

    fill_ft_kernel<<<(FT2R * FT2C + 255) / 256, 256, 0, stream>>>(FT2);

    if (dbuf) {
        // prologue: pure stage-1 for chunk 0 -> b0
        {
            const int hi0 = ((int)cm < MMAX) ? (int)cm : MMAX;
            fused_kernel<<<dim3(192), 512, 0, stream>>>(x, FT2, w, out,
                b0, b0, 0, 0, 0, 0, 0, hi0);
        }
        for (int i = 0; i < nc; ++i) {
            const int m0  = i * (int)cm;
            const int mhi = (m0 + (int)cm < MMAX) ? (m0 + (int)cm) : MMAX;
            short* eoR = (i & 1) ? b1 : b0;
            short* eoW = (i & 1) ? b0 : b1;      // next chunk's buffer
            const int nt  = ntilesf(m0, mhi);
            const int nb2 = (nt + 1) / 2;
            const bool hasn = (i + 1) < nc;
            const int n0 = (i + 1) * (int)cm;
            const int n1 = (n0 + (int)cm < MMAX) ? (n0 + (int)cm) : MMAX;
            fused_kernel<<<dim3(nb2 + (hasn ? 192 : 0)), 512, 0, stream>>>(
                x, FT2, w, out, eoR, eoW,
                m0, mhi, nb2, nt,
                hasn ? n0 : 0, hasn ? n1 : 0);
        }
    } else {
        // serial fallback: alternate pure-s1 / pure-s2 on single buffer
        for (int i = 0; i < nc; ++i) {
            const int m0  = i * (int)cm;
            const int mhi = (m0 + (int)cm < MMAX) ? (m0 + (int)cm) : MMAX;
            fused_kernel<<<dim3(192), 512, 0, stream>>>(x, FT2, w, out,
                b0, b0, 0, 0, 0, 0, m0, mhi);
            const int nt  = ntilesf(m0, mhi);
            const int nb2 = (nt + 1) / 2;
            fused_kernel<<<dim3(nb2), 512, 0, stream>>>(x, FT2, w, out,
                b0, b0, m0, mhi, nb2, nt, 0, 0);
        }
    }
}

// Round 23
// 60.218 us; speedup vs baseline: 1.4457x; 1.4457x over previous
//
#include <hip/hip_runtime.h>
#include <math.h>

#define NLAT 360
#define NLON 720
#define LMAX 360
#define MMAX 361
#define KPADC 384   // stage-1 C-col space per bc: 192 kf x 2 (s)
#define KFP  192    // folded-k padded length (180 data + 12 zero pad)
#define FT2C 192    // radix-4 folded DFT cols (181 data + 11 zero pad)
#define FT2R 368    // FT rows (361 data + 7 zero pad)
#define NJ   32
#define PS   200    // Xs col stride (shorts): 100 dwords = 4 mod 32 -> 2-way banks
#define YST  72     // Ys row stride (shorts)

typedef __attribute__((ext_vector_type(4))) float f32x4;
typedef __attribute__((ext_vector_type(8))) short bf16x8;

__device__ __forceinline__ short f2bf(float f) {
    union { float f; unsigned u; } v; v.f = f;
    unsigned r = (v.u + 0x7FFFu + ((v.u >> 16) & 1u)) >> 16;
    return (short)r;
}

// --- kernel 0: radix-4 folded bf16 cosine-DFT matrix FT[m][n3], pads = 0 ---
// FT[m][n3] = (2pi/720)*cos(2pi*m*n3/720), n3 in [0,180]; the x-folds supply
// (-1)^m for n>=360 and the n' <-> 360-n' symmetry (even m: +, odd m: -).
__global__ __launch_bounds__(256) void fill_ft_kernel(short* __restrict__ FT2) {
    int idx = blockIdx.x * 256 + threadIdx.x;
    const int total = FT2R * FT2C;
    if (idx >= total) return;
    int n = idx % FT2C;
    int m = idx / FT2C;
    short val = 0;
    if (m < MMAX && n <= 180) {
        int t = (m * n) % NLON;
        float s, c;
        sincospif((float)t / 360.0f, &s, &c);
        val = f2bf((6.283185307179586f / 720.0f) * c);
    }
    FT2[idx] = val;
}

// ---------------- stage 1: x-panel DFT, radix-4 n-fold + k-fold ------------
// Staging: plane0[n3] = (x[n3]+x[n3+360]) + (x[360-n3]+x[720-n3])  (even m)
//          plane1[n3] = (x[n3]-x[n3+360]) - (x[360-n3]-x[720-n3])  (odd m)
// n3 in [0,180], unpaired edges n3=0,180 carry no reverse term.
// Compute: 6 K-steps; even-m rows x plane0, odd-m rows x plane1.
// Epilogue (k-fold + Ys transpose + coalesced EO store) identical to r17-r21.
__global__ __launch_bounds__(512) void stage1_kernel(const float* __restrict__ x,
                                                     const short* __restrict__ FT2,
                                                     short* __restrict__ EO,
                                                     int m0, int cm) {
    __shared__ __align__(16) short Xs[2][64][PS];   // 51,200 B
    __shared__ __align__(16) short Ys[256 * YST];   // 36,864 B
    const int tid  = threadIdx.x;
    const int wav  = tid >> 6;
    const int lane = tid & 63;
    const int col0 = blockIdx.x * 64;
    const int m_hi = (m0 + cm < MMAX) ? (m0 + cm) : MMAX;

    const int bc_blk = col0 / KPADC;          // 384 % 64 == 0: one bc per block
    const int kf0    = (col0 - bc_blk * KPADC) >> 1;

    // staging: 64 rows x 24 chunks of 8 n3 (181 data + 11 zero-pad cols)
    for (int p = tid; p < 64 * 24; p += 512) {
        const int row = p / 24;
        const int c   = p - row * 24;
        const int gb  = col0 + row;
        const int bc  = gb / KPADC;
        const int q   = gb - bc * KPADC;
        const int kf  = q >> 1;
        const int s   = q & 1;
        const int klat = s ? (NLAT - 1 - kf) : kf;
        bf16x8 sv = {0,0,0,0,0,0,0,0}, dv = {0,0,0,0,0,0,0,0};
        if (kf < 180) {
            const float* xp = x + ((size_t)bc * NLAT + klat) * NLON;
            const int n0 = c * 8;
            f32x4 f0 = *(const f32x4*)(xp + n0);
            f32x4 f1 = *(const f32x4*)(xp + n0 + 4);
            f32x4 g0 = *(const f32x4*)(xp + n0 + 360);
            f32x4 g1 = *(const f32x4*)(xp + n0 + 364);
            // reverse windows (16B-aligned): v[j]=x[352-n0+j], w[j]=x[712-n0+j]
            f32x4 v0 = *(const f32x4*)(xp + 352 - n0);
            f32x4 v1 = *(const f32x4*)(xp + 356 - n0);
            f32x4 w0 = *(const f32x4*)(xp + 712 - n0);
            f32x4 w1 = *(const f32x4*)(xp + 716 - n0);
            const float t360 = xp[360 - n0];
            const float t720 = (c > 0) ? xp[720 - n0] : 0.0f;  // c==0: masked below
            #pragma unroll
            for (int e = 0; e < 8; ++e) {
                const int n3 = n0 + e;
                const float a = (e < 4) ? f0[e] : f1[e - 4];
                const float b = (e < 4) ? g0[e] : g1[e - 4];
                // x[360-n3]: e==0 -> t360, else v[8-e]; x[720-n3]: e==0 -> t720, else w[8-e]
                float r3 = (e == 0) ? t360 : ((8 - e < 4) ? v0[(8 - e) & 3] : v1[(8 - e) & 3]);
                float r7 = (e == 0) ? t720 : ((8 - e < 4) ? w0[(8 - e) & 3] : w1[(8 - e) & 3]);
                if (n3 == 0 || n3 == 180) { r3 = 0.0f; r7 = 0.0f; }   // unpaired edges
                sv[e] = f2bf((a + b) + (r3 + r7));
                dv[e] = f2bf((a - b) - (r3 - r7));
            }
        }
        *(bf16x8*)&Xs[0][row][c * 8] = sv;
        *(bf16x8*)&Xs[1][row][c * 8] = dv;
    }
    __syncthreads();

    const int r    = lane & 15;
    const int kg   = (lane >> 4) * 8;
    const int rowg = (lane >> 4) * 4;

    for (int mb = m0; mb < m_hi; mb += 256) {
        const int mwb = mb + wav * 32;
        const bool active = (mwb < m_hi);      // wave-uniform

        if (active) {
            int mE = mwb + 2 * r;     if (mE > FT2R - 1) mE = FT2R - 1;   // pad rows are 0
            int mO = mwb + 2 * r + 1; if (mO > FT2R - 1) mO = FT2R - 1;
            const short* ape = FT2 + (size_t)mE * FT2C + kg;
            const short* apo = FT2 + (size_t)mO * FT2C + kg;

            f32x4 accE[4] = {{0,0,0,0},{0,0,0,0},{0,0,0,0},{0,0,0,0}};
            f32x4 accO[4] = {{0,0,0,0},{0,0,0,0},{0,0,0,0},{0,0,0,0}};

            bf16x8 AEc = *(const bf16x8*)ape;
            bf16x8 AOc = *(const bf16x8*)apo;
            #pragma unroll
            for (int t = 0; t < 6; ++t) {
                bf16x8 AEn, AOn;
                if (t < 5) {
                    AEn = *(const bf16x8*)(ape + (t + 1) * 32);
                    AOn = *(const bf16x8*)(apo + (t + 1) * 32);
                }
                #pragma unroll
                for (int f = 0; f < 4; ++f) {
                    bf16x8 bS = *(const bf16x8*)&Xs[0][f * 16 + r][t * 32 + kg];
                    bf16x8 bD = *(const bf16x8*)&Xs[1][f * 16 + r][t * 32 + kg];
                    accE[f] = __builtin_amdgcn_mfma_f32_16x16x32_bf16(AEc, bS, accE[f], 0, 0, 0);
                    accO[f] = __builtin_amdgcn_mfma_f32_16x16x32_bf16(AOc, bD, accO[f], 0, 0, 0);
                }
                AEc = AEn; AOc = AOn;
            }

            // k-fold across adjacent lanes; Ys rows m_loc = wav*32 + 2R (+1)
            #pragma unroll
            for (int f = 0; f < 4; ++f) {
                const int kfl = (f * 16 + r) >> 1;
                const int e   = r & 1;
                const int yo  = e * 32 + kfl;
                #pragma unroll
                for (int i = 0; i < 4; ++i) {
                    float vE = accE[f][i];
                    float pE = __shfl_xor(vE, 1);
                    float valE = e ? (pE - vE) : (vE + pE);
                    float vO = accO[f][i];
                    float pO = __shfl_xor(vO, 1);
                    float valO = e ? (pO - vO) : (vO + pO);
                    const int mlE = wav * 32 + 2 * (rowg + i);
                    Ys[(size_t)mlE * YST + yo]       = f2bf(valE);
                    Ys[(size_t)(mlE + 1) * YST + yo] = f2bf(valO);
                }
            }
        }
        __syncthreads();

        // coalesced EO store: thread -> (m_loc, e); one full 64B line each
        {
            const int m_loc = tid >> 1;
            const int e     = tid & 1;
            const int mg    = mb + m_loc;
            if (mg < m_hi) {
                const short* src = &Ys[m_loc * YST + e * 32];
                short* dst = EO + (((size_t)(mg - m0) * 2 + e) * NJ + bc_blk) * KFP + kf0;
                #pragma unroll
                for (int j = 0; j < 4; ++j)
                    *(bf16x8*)(dst + j * 8) = *(const bf16x8*)(src + j * 8);
            }
        }
        __syncthreads();
    }
}

// ---------------- stage 2: r17-r21 champion verbatim (4-m tiles, 3-deep) ---
#define S2_GW(P, T)                                                             \
  { P##wa = *(const f32x4*)(wsp0 + (T) * 32);                                   \
    P##wb = *(const f32x4*)(wsp0 + (T) * 32 + 4);                               \
    P##wc = *(const f32x4*)(wsp1 + (T) * 32);                                   \
    P##wd = *(const f32x4*)(wsp1 + (T) * 32 + 4); }

#define S2_GB(P, T)                                                             \
  { P##ba = *(const bf16x8*)(be0 + (T) * 32);                                   \
    P##bb = *(const bf16x8*)(be1 + (T) * 32);                                   \
    P##bc = *(const bf16x8*)(bo0 + (T) * 32);                                   \
    P##bd = *(const bf16x8*)(bo1 + (T) * 32); }

#define S2_WRT(P, BUF)                                                          \
  { bf16x8 h0, h1;                                                              \
    _Pragma("unroll")                                                           \
    for (int e = 0; e < 4; ++e) {                                               \
      h0[e] = f2bf(P##wa[e]); h0[e + 4] = f2bf(P##wb[e]);                       \
      h1[e] = f2bf(P##wc[e]); h1[e + 4] = f2bf(P##wd[e]);                       \
    }                                                                           \
    *(bf16x8*)&Wl[BUF][ldso0] = h0;                                             \
    *(bf16x8*)&Wl[BUF][ldso1] = h1; }

#define S2_SYNC                                                                 \
    asm volatile("s_waitcnt lgkmcnt(0)" ::: "memory");                          \
    __builtin_amdgcn_s_barrier();                                               \
    __builtin_amdgcn_sched_barrier(0);

#define S2_CMP(P, BUF)                                                          \
  { bf16x8 aEf = *(const bf16x8*)&Wl[BUF][aEo];                                 \
    bf16x8 aOf = *(const bf16x8*)&Wl[BUF][aOo];                                 \
    accE0 = __builtin_amdgcn_mfma_f32_16x16x32_bf16(aEf, P##ba, accE0, 0, 0, 0);\
    accE1 = __builtin_amdgcn_mfma_f32_16x16x32_bf16(aEf, P##bb, accE1, 0, 0, 0);\
    accO0 = __builtin_amdgcn_mfma_f32_16x16x32_bf16(aOf, P##bc, accO0, 0, 0, 0);\
    accO1 = __builtin_amdgcn_mfma_f32_16x16x32_bf16(aOf, P##bd, accO1, 0, 0, 0);}

__global__ __launch_bounds__(256) void stage2_kernel(const float* __restrict__ W,
                                                     const short* __restrict__ EO,
                                                     float* __restrict__ out,
                                                     int m0, int m_hi) {
    __shared__ __align__(16) short Wl[2][4 * 2 * 17 * 40];   // 2 x 10,880 B

    int bid = blockIdx.x;
    int mt = 0;
    for (;;) {
        const int c = 12 - ((m0 + mt * 4) >> 5);
        if (bid < c) break;
        bid -= c; ++mt;
    }
    const int ltile = ((m0 + mt * 4) >> 5) + bid;
    const int l0 = ltile * 32;                  // even
    const int mb = m0 + mt * 4;

    const int tid  = threadIdx.x;
    const int wav  = tid >> 6;                  // 0..3 = m offset
    const int lane = tid & 63;
    const int r    = lane & 15;
    const int kg   = (lane >> 4) * 8;

    const int m    = mb + wav;
    const int mc   = (m < m_hi) ? m : (m_hi - 1);
    const int par  = mc & 1;
    const int mloc = mc - m0;

    const int srr = tid >> 2;
    const int sq  = (tid & 3) * 8;
    const int moff0 = srr >> 5,        loff0 = srr & 31;
    const int moff1 = (64 + srr) >> 5, loff1 = (64 + srr) & 31;
    int mst0 = mb + moff0; if (mst0 > MMAX - 1) mst0 = MMAX - 1;
    int mst1 = mb + moff1; if (mst1 > MMAX - 1) mst1 = MMAX - 1;
    int lst0 = l0 + loff0; if (lst0 > LMAX - 1) lst0 = LMAX - 1;
    int lst1 = l0 + loff1; if (lst1 > LMAX - 1) lst1 = LMAX - 1;
    const float* wsp0 = W + ((size_t)mst0 * LMAX + lst0) * NLAT + sq;
    const float* wsp1 = W + ((size_t)mst1 * LMAX + lst1) * NLAT + sq;
    const int ldso0 = ((moff0 * 2 + (loff0 & 1)) * 17 + (loff0 >> 1)) * 40 + sq;
    const int ldso1 = ((moff1 * 2 + (loff1 & 1)) * 17 + (loff1 >> 1)) * 40 + sq;

    const short* be0 = EO + (((size_t)mloc * 2 + 0) * NJ + r)      * KFP + kg;
    const short* be1 = EO + (((size_t)mloc * 2 + 0) * NJ + 16 + r) * KFP + kg;
    const short* bo0 = EO + (((size_t)mloc * 2 + 1) * NJ + r)      * KFP + kg;
    const short* bo1 = EO + (((size_t)mloc * 2 + 1) * NJ + 16 + r) * KFP + kg;

    const int aEo = ((wav * 2 + par) * 17 + r) * 40 + kg;
    const int aOo = ((wav * 2 + (1 - par)) * 17 + r) * 40 + kg;

    f32x4 accE0 = {0,0,0,0}, accE1 = {0,0,0,0}, accO0 = {0,0,0,0}, accO1 = {0,0,0,0};

    f32x4 Awa, Awb, Awc, Awd, Bwa, Bwb, Bwc, Bwd, Cwa, Cwb, Cwc, Cwd;
    bf16x8 Aba, Abb, Abc, Abd, Bba, Bbb, Bbc, Bbd, Cba, Cbb, Cbc, Cbd;

    S2_GW(A, 0); S2_GB(A, 0);
    S2_GW(B, 1); S2_GB(B, 1);
    S2_GW(C, 2); S2_GB(C, 2);

    S2_WRT(A, 0); S2_SYNC; S2_CMP(A, 0); S2_GW(A, 3); S2_GB(A, 3);
    S2_WRT(B, 1); S2_SYNC; S2_CMP(B, 1); S2_GW(B, 4); S2_GB(B, 4);
    S2_WRT(C, 0); S2_SYNC; S2_CMP(C, 0); S2_GW(C, 5); S2_GB(C, 5);
    S2_WRT(A, 1); S2_SYNC; S2_CMP(A, 1);
    S2_WRT(B, 0); S2_SYNC; S2_CMP(B, 0);
    S2_WRT(C, 1); S2_SYNC; S2_CMP(C, 1);

    const int rowg = (lane >> 4) * 4;
    if (m < m_hi) {
        #pragma unroll
        for (int i = 0; i < 4; ++i) {
            const int R  = rowg + i;
            const int le = l0 + par + 2 * R;
            const int lo = l0 + 1 - par + 2 * R;
            const size_t b0 = (size_t)r * LMAX;
            const size_t b1 = (size_t)(16 + r) * LMAX;
            if (le < LMAX) {
                out[(b0 + le) * MMAX + m] = accE0[i];
                out[(b1 + le) * MMAX + m] = accE1[i];
            }
            if (lo < LMAX) {
                out[(b0 + lo) * MMAX + m] = accO0[i];
                out[(b1 + lo) * MMAX + m] = accO1[i];
            }
        }
    }
}

extern "C" void kernel_launch(void* const* d_in, const int* in_sizes, int n_in,
                              void* d_out, int out_size, void* d_ws, size_t ws_size,
                              hipStream_t stream) {
    const float* x = (const float*)d_in[0];
    const float* w = (const float*)d_in[1];
    float* out = (float*)d_out;

    const size_t XR_OFF = (size_t)FT2R * FT2C * 2;   // 141,312 B
    const size_t PER_M  = (size_t)2 * NJ * KFP * 2;  // 24,576 B per mode
    long cm = 0;
    if (d_ws != nullptr && ws_size > XR_OFF + PER_M) cm = (long)((ws_size - XR_OFF) / PER_M);
    if (cm > MMAX) cm = MMAX;
    if (cm < 1) return;

    short* FT2 = (short*)d_ws;
    short* EO  = (short*)((char*)d_ws + XR_OFF);
    fill_ft_kernel<<<(FT2R * FT2C + 255) / 256, 256, 0, stream>>>(FT2);
    for (int m0 = 0; m0 < MMAX; m0 += (int)cm) {
        const int cmx = ((int)cm < MMAX - m0) ? (int)cm : (MMAX - m0);
        stage1_kernel<<<dim3(192), 512, 0, stream>>>(x, FT2, EO, m0, cmx);
        const int gym = (cmx + 3) / 4;
        int nblk = 0;
        for (int mtt = 0; mtt < gym; ++mtt) nblk += 12 - ((m0 + mtt * 4) >> 5);
        stage2_kernel<<<dim3(nblk), 256, 0, stream>>>(w, EO, out, m0, m0 + cmx);
    }
}